// Round 1
// baseline (1237.752 us; speedup 1.0000x reference)
//
#include <hip/hip_runtime.h>
#include <cstdint>

#define T_STEPS 512
#define F 128            // IN_F == OUT_F
#define ROWS 16          // batch rows per block (one MFMA M-tile)
#define BLOCK 512        // 8 waves: wave = (gate 0..3, n-half 0..1)
#define FP  (F + 8)      // f16 LDS row stride: 272 B = 17*16B (aligned, bank-spread)
#define FPF (F + 4)      // f32 LDS row stride for preactivations

typedef __attribute__((ext_vector_type(8))) _Float16 half8;
typedef __attribute__((ext_vector_type(4))) float    f32x4;

__device__ __forceinline__ float sigmoidf_(float z) { return 1.f / (1.f + __expf(-z)); }
__device__ __forceinline__ float tanhf_(float z)    { return 2.f / (1.f + __expf(-2.f * z)) - 1.f; }

__global__ __launch_bounds__(BLOCK, 2)
void lstm_fused(const float* __restrict__ x,
                const float* __restrict__ wh_i, const float* __restrict__ wx_i, const float* __restrict__ b_i,
                const float* __restrict__ wh_f, const float* __restrict__ wx_f, const float* __restrict__ b_f,
                const float* __restrict__ wh_g, const float* __restrict__ wx_g, const float* __restrict__ b_g,
                const float* __restrict__ wh_o, const float* __restrict__ wx_o, const float* __restrict__ b_o,
                float* __restrict__ out)
{
    __shared__ _Float16 h_lds[ROWS * FP];        // h_{t-1}, fp16, A-layout-friendly
    __shared__ _Float16 x_lds[2][ROWS * FP];     // x_t double buffer
    __shared__ float    pre_lds[4][ROWS * FPF];  // gate preactivations (fp32)

    const int tid  = threadIdx.x;
    const int wave = tid >> 6;
    const int lane = tid & 63;
    const int quad = lane >> 4;
    const int l16  = lane & 15;
    const int gate = wave & 3;      // 0=ig 1=fg 2=in 3=og
    const int nh   = wave >> 2;     // output-feature half
    const int row0 = blockIdx.x * ROWS;

    const float* whp = (gate == 0) ? wh_i : (gate == 1) ? wh_f : (gate == 2) ? wh_g : wh_o;
    const float* wxp = (gate == 0) ? wx_i : (gate == 1) ? wx_f : (gate == 2) ? wx_g : wx_o;
    const float* bp  = (gate == 0) ? b_i  : (gate == 1) ? b_f  : (gate == 2) ? b_g  : b_o;

    // ---- load weights once into VGPR B-fragments: B[k=kc*32+quad*8+j][n=nh*64+nt*16+l16]
    half8 whfr[4][4], wxfr[4][4];
    float bias_v[4];
    #pragma unroll
    for (int nt = 0; nt < 4; ++nt) {
        const int ncol = nh * 64 + nt * 16 + l16;
        bias_v[nt] = bp[ncol];
        #pragma unroll
        for (int kc = 0; kc < 4; ++kc) {
            half8 a, b;
            #pragma unroll
            for (int j = 0; j < 8; ++j) {
                const int k = kc * 32 + quad * 8 + j;
                a[j] = (_Float16)whp[k * F + ncol];
                b[j] = (_Float16)wxp[k * F + ncol];
            }
            whfr[kc][nt] = a;
            wxfr[kc][nt] = b;
        }
    }

    // ---- per-thread elementwise ownership: 4 (row,feat) pairs
    int erow[4], efeat[4];
    float c_st[4] = {0.f, 0.f, 0.f, 0.f};
    float h_out[4] = {0.f, 0.f, 0.f, 0.f};
    #pragma unroll
    for (int i = 0; i < 4; ++i) {
        const int p = tid + i * BLOCK;
        erow[i]  = p >> 7;
        efeat[i] = p & 127;
    }

    // ---- init: h = 0, stage x_0
    #pragma unroll
    for (int i = 0; i < 4; ++i) {
        h_lds[erow[i] * FP + efeat[i]] = (_Float16)0.f;
        x_lds[0][erow[i] * FP + efeat[i]] =
            (_Float16)x[(size_t)(row0 + erow[i]) * (T_STEPS * F) + efeat[i]];
    }
    __syncthreads();

    for (int t = 0; t < T_STEPS; ++t) {
        const int buf = t & 1;

        // A-fragments: A[m=l16][k], 8 contiguous fp16 per read
        half8 ah[4], ax[4];
        #pragma unroll
        for (int kc = 0; kc < 4; ++kc) {
            ah[kc] = *(const half8*)&h_lds[l16 * FP + kc * 32 + quad * 8];
            ax[kc] = *(const half8*)&x_lds[buf][l16 * FP + kc * 32 + quad * 8];
        }

        // prefetch x_{t+1} (hidden under MFMAs)
        float xn[4];
        if (t + 1 < T_STEPS) {
            #pragma unroll
            for (int i = 0; i < 4; ++i)
                xn[i] = x[(size_t)(row0 + erow[i]) * (T_STEPS * F) + (size_t)(t + 1) * F + efeat[i]];
        }

        // preact = bias + x_t @ Wx + h_{t-1} @ Wh   (fp32 accum)
        f32x4 acc[4];
        #pragma unroll
        for (int nt = 0; nt < 4; ++nt)
            acc[nt] = (f32x4){bias_v[nt], bias_v[nt], bias_v[nt], bias_v[nt]};
        #pragma unroll
        for (int kc = 0; kc < 4; ++kc) {
            #pragma unroll
            for (int nt = 0; nt < 4; ++nt)
                acc[nt] = __builtin_amdgcn_mfma_f32_16x16x32_f16(ax[kc], wxfr[kc][nt], acc[nt], 0, 0, 0);
        }
        #pragma unroll
        for (int kc = 0; kc < 4; ++kc) {
            #pragma unroll
            for (int nt = 0; nt < 4; ++nt)
                acc[nt] = __builtin_amdgcn_mfma_f32_16x16x32_f16(ah[kc], whfr[kc][nt], acc[nt], 0, 0, 0);
        }

        // C-frag -> LDS: D[row=quad*4+r][col=l16]
        #pragma unroll
        for (int nt = 0; nt < 4; ++nt) {
            #pragma unroll
            for (int r = 0; r < 4; ++r)
                pre_lds[gate][(quad * 4 + r) * FPF + nh * 64 + nt * 16 + l16] = acc[nt][r];
        }
        __syncthreads();

        // elementwise gates + state update
        #pragma unroll
        for (int i = 0; i < 4; ++i) {
            const int rf = erow[i] * FPF + efeat[i];
            const float zi = pre_lds[0][rf];
            const float zf = pre_lds[1][rf];
            const float zg = pre_lds[2][rf];
            const float zo = pre_lds[3][rf];
            const float ig = sigmoidf_(zi);
            const float fg = sigmoidf_(zf);
            const float gt = tanhf_(zg);
            const float ot = sigmoidf_(zo);
            c_st[i] = fg * c_st[i] + ig * gt;
            const float hh = ot * tanhf_(c_st[i]);
            h_out[i] = hh;
            h_lds[erow[i] * FP + efeat[i]] = (_Float16)hh;
            if (t + 1 < T_STEPS)
                x_lds[1 - buf][erow[i] * FP + efeat[i]] = (_Float16)xn[i];
        }
        __syncthreads();
    }

    #pragma unroll
    for (int i = 0; i < 4; ++i)
        out[(size_t)(row0 + erow[i]) * F + efeat[i]] = h_out[i];
}

extern "C" void kernel_launch(void* const* d_in, const int* in_sizes, int n_in,
                              void* d_out, int out_size, void* d_ws, size_t ws_size,
                              hipStream_t stream) {
    const float* x   = (const float*)d_in[0];
    const float* whi = (const float*)d_in[1];
    const float* wxi = (const float*)d_in[2];
    const float* bi  = (const float*)d_in[3];
    const float* whf = (const float*)d_in[4];
    const float* wxf = (const float*)d_in[5];
    const float* bf  = (const float*)d_in[6];
    const float* whg = (const float*)d_in[7];
    const float* wxg = (const float*)d_in[8];
    const float* bg  = (const float*)d_in[9];
    const float* who = (const float*)d_in[10];
    const float* wxo = (const float*)d_in[11];
    const float* bo  = (const float*)d_in[12];
    float* out = (float*)d_out;

    hipLaunchKernelGGL(lstm_fused, dim3(512 / ROWS), dim3(BLOCK), 0, stream,
                       x, whi, wxi, bi, whf, wxf, bf, whg, wxg, bg, who, wxo, bo, out);
}

// Round 2
// 840.358 us; speedup vs baseline: 1.4729x; 1.4729x over previous
//
#include <hip/hip_runtime.h>
#include <cstdint>
#include <cstddef>

#define T_STEPS 512
#define BATCH 512
#define F 128
#define ROWS 16
#define NBT (BATCH / ROWS)     // 32 batch tiles
#define BLOCK 512              // 8 waves
#define FP (F + 8)             // fp16 LDS row stride (conflict-spread)
#define FPF (F + 4)
#define TT 16                  // t-steps per producer block
#define L2E 1.4426950408889634f

typedef __attribute__((ext_vector_type(8))) _Float16 half8;
typedef __attribute__((ext_vector_type(4))) _Float16 half4;
typedef __attribute__((ext_vector_type(4))) float    f32x4;

__device__ __forceinline__ float frcp_(float x)  { return __builtin_amdgcn_rcpf(x); }
__device__ __forceinline__ float fexp2_(float x) { return __builtin_amdgcn_exp2f(x); }

// ============================================================================
// Producer: xp[t][bt][g] = fp16( x_tile @ Wx_g + b_g ), stored [col128][row16]
// so the scan's per-lane load (rows quad*4..+3, col ncol) is one contiguous 8B.
// ============================================================================
__global__ __launch_bounds__(BLOCK, 4)
void xproj_gemm(const float* __restrict__ x,
                const float* __restrict__ wx0, const float* __restrict__ b0,
                const float* __restrict__ wx1, const float* __restrict__ b1,
                const float* __restrict__ wx2, const float* __restrict__ b2,
                const float* __restrict__ wx3, const float* __restrict__ b3,
                _Float16* __restrict__ xp)
{
    const int tid  = threadIdx.x;
    const int w    = tid >> 6;
    const int lane = tid & 63;
    const int quad = lane >> 4;
    const int l16  = lane & 15;
    const int bt   = blockIdx.x & (NBT - 1);
    const int tc   = blockIdx.x >> 5;          // NBT == 32
    const int row0 = bt * ROWS;
    const int ncol = w * 16 + l16;

    const float* wxp[4] = {wx0, wx1, wx2, wx3};
    const float* bpp[4] = {b0, b1, b2, b3};

    // B-fragments for all 4 gates: B[k=kc*32+quad*8+j][n=ncol]
    half8 bfr[4][4];
    float bias_v[4];
    #pragma unroll
    for (int g = 0; g < 4; ++g) {
        bias_v[g] = bpp[g][ncol];
        #pragma unroll
        for (int kc = 0; kc < 4; ++kc) {
            half8 v;
            #pragma unroll
            for (int j = 0; j < 8; ++j)
                v[j] = (_Float16)wxp[g][(kc * 32 + quad * 8 + j) * F + ncol];
            bfr[g][kc] = v;
        }
    }

    for (int tl = 0; tl < TT; ++tl) {
        const int t = tc * TT + tl;
        // A-fragment: A[m=l16][k=kc*32+quad*8+j], rows = batch rows of this tile
        half8 afr[4];
        #pragma unroll
        for (int kc = 0; kc < 4; ++kc) {
            const float* px = &x[(size_t)(row0 + l16) * (T_STEPS * F)
                                 + (size_t)t * F + kc * 32 + quad * 8];
            const f32x4 u0 = *(const f32x4*)px;
            const f32x4 u1 = *(const f32x4*)(px + 4);
            half8 v;
            #pragma unroll
            for (int j = 0; j < 4; ++j) { v[j] = (_Float16)u0[j]; v[4 + j] = (_Float16)u1[j]; }
            afr[kc] = v;
        }

        f32x4 acc[4];
        #pragma unroll
        for (int g = 0; g < 4; ++g)
            acc[g] = (f32x4){bias_v[g], bias_v[g], bias_v[g], bias_v[g]};
        #pragma unroll
        for (int kc = 0; kc < 4; ++kc) {
            #pragma unroll
            for (int g = 0; g < 4; ++g)
                acc[g] = __builtin_amdgcn_mfma_f32_16x16x32_f16(afr[kc], bfr[g][kc], acc[g], 0, 0, 0);
        }

        #pragma unroll
        for (int g = 0; g < 4; ++g) {
            half4 hv;
            #pragma unroll
            for (int r = 0; r < 4; ++r) hv[r] = (_Float16)acc[g][r];
            const size_t off = ((((size_t)t * NBT + bt) * 4 + g) * (size_t)(F * ROWS))
                               + (size_t)ncol * ROWS + quad * 4;
            *(half4*)&xp[off] = hv;
        }
    }
}

// ============================================================================
// Scan: 32 blocks (one per batch tile). Wave owns 16 cols for ALL 4 gates →
// elementwise in C-fragment registers, h double-buffered in LDS, 1 barrier/step.
// ============================================================================
__global__ __launch_bounds__(BLOCK, 2)
void lstm_scan(const _Float16* __restrict__ xp,
               const float* __restrict__ wh0, const float* __restrict__ wh1,
               const float* __restrict__ wh2, const float* __restrict__ wh3,
               float* __restrict__ out)
{
    __shared__ _Float16 h_lds[2][ROWS * FP];

    const int tid  = threadIdx.x;
    const int w    = tid >> 6;
    const int lane = tid & 63;
    const int quad = lane >> 4;
    const int l16  = lane & 15;
    const int bt   = blockIdx.x;
    const int row0 = bt * ROWS;
    const int ncol = w * 16 + l16;

    const float* whp[4] = {wh0, wh1, wh2, wh3};
    half8 whfr[4][4];
    #pragma unroll
    for (int g = 0; g < 4; ++g) {
        #pragma unroll
        for (int kc = 0; kc < 4; ++kc) {
            half8 v;
            #pragma unroll
            for (int j = 0; j < 8; ++j)
                v[j] = (_Float16)whp[g][(kc * 32 + quad * 8 + j) * F + ncol];
            whfr[g][kc] = v;
        }
    }

    for (int i = tid; i < ROWS * FP; i += BLOCK) h_lds[0][i] = (_Float16)0.f;

    const size_t lane_off = (size_t)ncol * ROWS + quad * 4;
    // prefetch xp for t=0,1
    half4 xbuf[2][4];
    #pragma unroll
    for (int g = 0; g < 4; ++g)
        xbuf[0][g] = *(const half4*)&xp[(((size_t)0 * NBT + bt) * 4 + g) * (F * ROWS) + lane_off];
    #pragma unroll
    for (int g = 0; g < 4; ++g)
        xbuf[1][g] = *(const half4*)&xp[(((size_t)1 * NBT + bt) * 4 + g) * (F * ROWS) + lane_off];

    float c_st[4] = {0.f, 0.f, 0.f, 0.f};
    float h_f[4]  = {0.f, 0.f, 0.f, 0.f};
    __syncthreads();

    #pragma unroll 2
    for (int t = 0; t < T_STEPS; ++t) {
        const int cur = t & 1;

        // A-fragment of h_{t-1}
        half8 ah[4];
        #pragma unroll
        for (int kc = 0; kc < 4; ++kc)
            ah[kc] = *(const half8*)&h_lds[cur][l16 * FP + kc * 32 + quad * 8];

        // acc init = x-projection (bias folded in by producer)
        f32x4 acc[4];
        #pragma unroll
        for (int g = 0; g < 4; ++g) {
            #pragma unroll
            for (int r = 0; r < 4; ++r) acc[g][r] = (float)xbuf[cur][g][r];
        }

        // prefetch xp for t+2 into the slot just consumed
        if (t + 2 < T_STEPS) {
            #pragma unroll
            for (int g = 0; g < 4; ++g)
                xbuf[cur][g] = *(const half4*)
                    &xp[(((size_t)(t + 2) * NBT + bt) * 4 + g) * (F * ROWS) + lane_off];
        }

        // h @ Wh for all gates: 16 MFMAs, 4 independent chains
        #pragma unroll
        for (int kc = 0; kc < 4; ++kc) {
            #pragma unroll
            for (int g = 0; g < 4; ++g)
                acc[g] = __builtin_amdgcn_mfma_f32_16x16x32_f16(ah[kc], whfr[g][kc], acc[g], 0, 0, 0);
        }

        // elementwise in C-layout registers (rows quad*4+r, col ncol)
        #pragma unroll
        for (int r = 0; r < 4; ++r) {
            const float zi = acc[0][r], zf = acc[1][r], zg = acc[2][r], zo = acc[3][r];
            const float ai = fexp2_(-__builtin_fabsf(zi) * L2E);
            const float af = fexp2_(-__builtin_fabsf(zf) * L2E);
            const float ag = fexp2_(-__builtin_fabsf(zg) * (2.f * L2E));
            const float ao = fexp2_(-__builtin_fabsf(zo) * L2E);
            const float d1 = 1.f + ai, d2 = 1.f + af, d3 = 1.f + ao, d4 = 1.f + ag;
            const float s3 = d3 * d4, s2 = d2 * s3;
            const float rP = frcp_(d1 * s2);       // one rcp for 4 denominators
            const float inv1 = rP * s2;
            const float q1 = rP * d1;
            const float inv2 = q1 * s3;
            const float q2 = q1 * d2;
            const float inv3 = q2 * d4, inv4 = q2 * d3;
            const float ig = (zi > 0.f ? 1.f : ai) * inv1;
            const float fg = (zf > 0.f ? 1.f : af) * inv2;
            const float ot = (zo > 0.f ? 1.f : ao) * inv3;
            const float gt = __builtin_copysignf((1.f - ag) * inv4, zg);
            const float cn = fg * c_st[r] + ig * gt;
            c_st[r] = cn;
            const float ac = fexp2_(-__builtin_fabsf(cn) * (2.f * L2E));
            const float th = __builtin_copysignf((1.f - ac) * frcp_(1.f + ac), cn);
            const float hh = ot * th;
            h_f[r] = hh;
            h_lds[cur ^ 1][(quad * 4 + r) * FP + ncol] = (_Float16)hh;
        }
        __syncthreads();
    }

    #pragma unroll
    for (int r = 0; r < 4; ++r)
        out[(size_t)(row0 + quad * 4 + r) * F + ncol] = h_f[r];
}

// ============================================================================
// Fallback (verified round-1 fused kernel) — used only if ws_size is too small.
// ============================================================================
__device__ __forceinline__ float sigmoidf_(float z) { return 1.f / (1.f + __expf(-z)); }
__device__ __forceinline__ float tanhf_(float z)    { return 2.f / (1.f + __expf(-2.f * z)) - 1.f; }

__global__ __launch_bounds__(BLOCK, 2)
void lstm_fused(const float* __restrict__ x,
                const float* __restrict__ wh_i, const float* __restrict__ wx_i, const float* __restrict__ b_i,
                const float* __restrict__ wh_f, const float* __restrict__ wx_f, const float* __restrict__ b_f,
                const float* __restrict__ wh_g, const float* __restrict__ wx_g, const float* __restrict__ b_g,
                const float* __restrict__ wh_o, const float* __restrict__ wx_o, const float* __restrict__ b_o,
                float* __restrict__ out)
{
    __shared__ _Float16 h_lds[ROWS * FP];
    __shared__ _Float16 x_lds[2][ROWS * FP];
    __shared__ float    pre_lds[4][ROWS * FPF];

    const int tid  = threadIdx.x;
    const int wave = tid >> 6;
    const int lane = tid & 63;
    const int quad = lane >> 4;
    const int l16  = lane & 15;
    const int gate = wave & 3;
    const int nh   = wave >> 2;
    const int row0 = blockIdx.x * ROWS;

    const float* whp = (gate == 0) ? wh_i : (gate == 1) ? wh_f : (gate == 2) ? wh_g : wh_o;
    const float* wxp = (gate == 0) ? wx_i : (gate == 1) ? wx_f : (gate == 2) ? wx_g : wx_o;
    const float* bp  = (gate == 0) ? b_i  : (gate == 1) ? b_f  : (gate == 2) ? b_g  : b_o;

    half8 whfr[4][4], wxfr[4][4];
    float bias_v[4];
    #pragma unroll
    for (int nt = 0; nt < 4; ++nt) {
        const int ncol = nh * 64 + nt * 16 + l16;
        bias_v[nt] = bp[ncol];
        #pragma unroll
        for (int kc = 0; kc < 4; ++kc) {
            half8 a, b;
            #pragma unroll
            for (int j = 0; j < 8; ++j) {
                const int k = kc * 32 + quad * 8 + j;
                a[j] = (_Float16)whp[k * F + ncol];
                b[j] = (_Float16)wxp[k * F + ncol];
            }
            whfr[kc][nt] = a;
            wxfr[kc][nt] = b;
        }
    }

    int erow[4], efeat[4];
    float c_st[4] = {0.f, 0.f, 0.f, 0.f};
    float h_out[4] = {0.f, 0.f, 0.f, 0.f};
    #pragma unroll
    for (int i = 0; i < 4; ++i) {
        const int p = tid + i * BLOCK;
        erow[i]  = p >> 7;
        efeat[i] = p & 127;
    }

    #pragma unroll
    for (int i = 0; i < 4; ++i) {
        h_lds[erow[i] * FP + efeat[i]] = (_Float16)0.f;
        x_lds[0][erow[i] * FP + efeat[i]] =
            (_Float16)x[(size_t)(row0 + erow[i]) * (T_STEPS * F) + efeat[i]];
    }
    __syncthreads();

    for (int t = 0; t < T_STEPS; ++t) {
        const int buf = t & 1;
        half8 ah[4], ax[4];
        #pragma unroll
        for (int kc = 0; kc < 4; ++kc) {
            ah[kc] = *(const half8*)&h_lds[l16 * FP + kc * 32 + quad * 8];
            ax[kc] = *(const half8*)&x_lds[buf][l16 * FP + kc * 32 + quad * 8];
        }
        float xn[4];
        if (t + 1 < T_STEPS) {
            #pragma unroll
            for (int i = 0; i < 4; ++i)
                xn[i] = x[(size_t)(row0 + erow[i]) * (T_STEPS * F) + (size_t)(t + 1) * F + efeat[i]];
        }
        f32x4 acc[4];
        #pragma unroll
        for (int nt = 0; nt < 4; ++nt)
            acc[nt] = (f32x4){bias_v[nt], bias_v[nt], bias_v[nt], bias_v[nt]};
        #pragma unroll
        for (int kc = 0; kc < 4; ++kc) {
            #pragma unroll
            for (int nt = 0; nt < 4; ++nt)
                acc[nt] = __builtin_amdgcn_mfma_f32_16x16x32_f16(ax[kc], wxfr[kc][nt], acc[nt], 0, 0, 0);
        }
        #pragma unroll
        for (int kc = 0; kc < 4; ++kc) {
            #pragma unroll
            for (int nt = 0; nt < 4; ++nt)
                acc[nt] = __builtin_amdgcn_mfma_f32_16x16x32_f16(ah[kc], whfr[kc][nt], acc[nt], 0, 0, 0);
        }
        #pragma unroll
        for (int nt = 0; nt < 4; ++nt) {
            #pragma unroll
            for (int r = 0; r < 4; ++r)
                pre_lds[gate][(quad * 4 + r) * FPF + nh * 64 + nt * 16 + l16] = acc[nt][r];
        }
        __syncthreads();
        #pragma unroll
        for (int i = 0; i < 4; ++i) {
            const int rf = erow[i] * FPF + efeat[i];
            const float zi = pre_lds[0][rf];
            const float zf = pre_lds[1][rf];
            const float zg = pre_lds[2][rf];
            const float zo = pre_lds[3][rf];
            const float ig = sigmoidf_(zi);
            const float fg = sigmoidf_(zf);
            const float gt = tanhf_(zg);
            const float ot = sigmoidf_(zo);
            c_st[i] = fg * c_st[i] + ig * gt;
            const float hh = ot * tanhf_(c_st[i]);
            h_out[i] = hh;
            h_lds[erow[i] * FP + efeat[i]] = (_Float16)hh;
            if (t + 1 < T_STEPS)
                x_lds[1 - buf][erow[i] * FP + efeat[i]] = (_Float16)xn[i];
        }
        __syncthreads();
    }

    #pragma unroll
    for (int i = 0; i < 4; ++i)
        out[(size_t)(row0 + erow[i]) * F + efeat[i]] = h_out[i];
}

extern "C" void kernel_launch(void* const* d_in, const int* in_sizes, int n_in,
                              void* d_out, int out_size, void* d_ws, size_t ws_size,
                              hipStream_t stream) {
    const float* x   = (const float*)d_in[0];
    const float* whi = (const float*)d_in[1];
    const float* wxi = (const float*)d_in[2];
    const float* bi  = (const float*)d_in[3];
    const float* whf = (const float*)d_in[4];
    const float* wxf = (const float*)d_in[5];
    const float* bf  = (const float*)d_in[6];
    const float* whg = (const float*)d_in[7];
    const float* wxg = (const float*)d_in[8];
    const float* bg  = (const float*)d_in[9];
    const float* who = (const float*)d_in[10];
    const float* wxo = (const float*)d_in[11];
    const float* bo  = (const float*)d_in[12];
    float* out = (float*)d_out;

    const size_t need = (size_t)T_STEPS * NBT * 4 * (F * ROWS) * sizeof(_Float16); // 256 MiB

    if (ws_size >= need) {
        _Float16* xp = (_Float16*)d_ws;
        hipLaunchKernelGGL(xproj_gemm, dim3(NBT * (T_STEPS / TT)), dim3(BLOCK), 0, stream,
                           x, wxi, bi, wxf, bf, wxg, bg, wxo, bo, xp);
        hipLaunchKernelGGL(lstm_scan, dim3(NBT), dim3(BLOCK), 0, stream,
                           xp, whi, whf, whg, who, out);
    } else {
        hipLaunchKernelGGL(lstm_fused, dim3(NBT), dim3(BLOCK), 0, stream,
                           x, whi, wxi, bi, whf, wxf, bf, whg, wxg, bg, who, wxo, bo, out);
    }
}